// Round 6
// baseline (352.999 us; speedup 1.0000x reference)
//
#include <hip/hip_runtime.h>

typedef unsigned short u16;
typedef unsigned int u32;
typedef __attribute__((ext_vector_type(8))) short short8;
typedef __attribute__((ext_vector_type(4))) float floatx4;

#define HEADS 8
#define DIM 512          // K for both GEMMs
#define HH 96
#define WW 96
#define NPIX 9216
#define M_TOT 36864
#define N_QKV 1536
#define SCALE 0.125f

__device__ __forceinline__ float b2f(u16 v){
    union{float f;u32 u;}x; x.u=((u32)v)<<16; return x.f;
}
__device__ __forceinline__ u16 f2b(float f){
    union{float f;u32 u;}x; x.f=f;
    u32 u=x.u + 0x7fffu + ((x.u>>16)&1u);
    return (u16)(u>>16);
}
// packed f32x2 -> bf16x2 (RNE, matches f2b bit-for-bit); no builtin on gfx950
__device__ __forceinline__ u32 pack2(float a,float b){
    u32 r; asm("v_cvt_pk_bf16_f32 %0, %1, %2" : "=v"(r) : "v"(a), "v"(b));
    return r;
}
__device__ __forceinline__ short8 mk8(u32 a,u32 b,u32 c,u32 d){
    union{u32 u[4]; short8 v;} x; x.u[0]=a; x.u[1]=b; x.u[2]=c; x.u[3]=d; return x.v;
}

// async global->LDS, 16 B per lane; lds dest = wave-uniform base + lane*16
__device__ __forceinline__ void gload16(const u16* g, u16* l){
    __builtin_amdgcn_global_load_lds(
        (const __attribute__((address_space(1))) u32*)g,
        (__attribute__((address_space(3))) u32*)l, 16, 0, 0);
}

// ---------------------------------------------------------------------------
// dtype detector (bf16 vs fp32 inputs)
// ---------------------------------------------------------------------------
__global__ void detect_dtype(const u16* __restrict__ wq, int* __restrict__ flag){
    __shared__ int cnt;
    if (threadIdx.x==0) cnt=0;
    __syncthreads();
    u16 u = wq[2*threadIdx.x];
    int e = (u>>7)&0xff;
    if (e>=100 && e<=128) atomicAdd(&cnt,1);
    __syncthreads();
    if (threadIdx.x==0) *flag = (cnt>128)?1:0;
}

// ---------------------------------------------------------------------------
// Weights -> bf16 (layout unchanged, [n][k] k-contiguous)
// ---------------------------------------------------------------------------
__global__ __launch_bounds__(256)
void convert_w(const void* __restrict__ wq, const void* __restrict__ wo,
               const int* __restrict__ flag, u16* __restrict__ wqb, u16* __restrict__ wob){
    const int isb = *flag;
    int i = blockIdx.x*256 + threadIdx.x;
    const int nq = N_QKV*DIM;                 // 786432
    if (i < nq){
        wqb[i] = isb ? ((const u16*)wq)[i] : f2b(((const float*)wq)[i]);
    } else {
        int j = i - nq;                       // < 262144
        wob[j] = isb ? ((const u16*)wo)[j] : f2b(((const float*)wo)[j]);
    }
}

// ---------------------------------------------------------------------------
// x [b][c][pix] (fp32 or bf16) -> xb [b*9216+pix][c] bf16   (transpose)
// ---------------------------------------------------------------------------
__global__ __launch_bounds__(256)
void convert_x(const void* __restrict__ xv, const int* __restrict__ flag,
               u16* __restrict__ xb){
    __shared__ u16 tile[64][65];
    const int isb = *flag;
    const int p0 = blockIdx.x*64, c0 = blockIdx.y*64, b = blockIdx.z;
    const int t = threadIdx.x;
    const int pl = t&63, c4 = t>>6;
    const float* x32 = (const float*)xv;
    const u16*   x16 = (const u16*)xv;
    size_t src = ((size_t)b*DIM + c0 + c4)*NPIX + p0 + pl;
    #pragma unroll
    for (int i=0;i<16;i++){
        int cl = c4 + i*4;
        size_t s = src + (size_t)i*4*NPIX;
        tile[cl][pl] = isb ? x16[s] : f2b(x32[s]);
    }
    __syncthreads();
    const int cu = t&31, r8 = t>>5;
    u32* xb32 = (u32*)xb;
    #pragma unroll
    for (int i=0;i<8;i++){
        int pr = r8 + i*8;
        u32 v = (u32)tile[2*cu][pr] | ((u32)tile[2*cu+1][pr]<<16);
        xb32[((size_t)b*NPIX + p0 + pr)*(DIM/2) + (c0>>1) + cu] = v;
    }
}

// ---------------------------------------------------------------------------
// FUSED QKV-GEMM + attention. One block per (bat, head, row): 3072 blocks,
// 6 waves (384 thr). Phase 1: 96x192 GEMM (Q|K|V for one head's row),
// BK=64 double-buffered LDS, counted vmcnt(6). Wave w owns n-tiles
// {2w, 2w+1} (= 32 of the 192 outputs). Phase 2: per-wave ct-transpose
// (R4-verified) writes Q/K/V chunk-fragment images into LDS (exact qkt/vtt
// layouts). Phase 3: wave w runs the R5-verified in-register attention for
// q-tile qt=w, reading chunks from LDS, storing attno directly.
// LDS 72KB -> 2 independent blocks/CU; 3072/512 = 6 exact rounds, no tail.
// qkt/vtt HBM roundtrip (110MB write + 113MB read) eliminated.
// Grid: xcd = id&7; same-row head-blocks grouped per XCD for x/W L2 reuse.
// ---------------------------------------------------------------------------
__global__ __launch_bounds__(384, 3)
void qkv_attn(const u16* __restrict__ xb, const u16* __restrict__ wqb,
              u16* __restrict__ attno){
    // [0..18431]  : staging buf0 (A 12KB @0, B 24KB @6144) / later QKV chunks
    //               (Q @0, K @6144, V @12288; 12 x 1KB chunks each)
    // [18432..36863]: staging buf1 / later per-wave f32 ct scratch (1152 u16 ea)
    __shared__ __align__(16) u16 lds[36864];           // 72 KiB
    const int t = threadIdx.x;
    const int w = t>>6, l = t&63, lr = l&15, lq = l>>4;
    const int id  = blockIdx.x;
    const int xcd = id & 7, s = id >> 3;               // 3072 = 8 x 384
    const int rowid = (s>>3)*8 + xcd;                  // 0..383; 8 heads of a
    const int head  = s & 7;                           // row land on one XCD
    const int bat = rowid / HH, row = rowid % HH;
    // ---- staging addresses (wave w stages A chunks {2w,2w+1}, B {4w..4w+3})
    const int sub0 = w*2, sub1 = w*2+1;                // B n-tiles (= compute tiles)
    const u16* gA0k = xb + ((size_t)bat*NPIX + row*WW + w*16 + lr)*DIM + lq*8;
    const u16* gB00 = wqb + (size_t)((sub0>>2)*512 + head*64 + (sub0&3)*16 + lr)*DIM + lq*8;
    const u16* gB10 = wqb + (size_t)((sub1>>2)*512 + head*64 + (sub1&3)*16 + lr)*DIM + lq*8;
    const int la0 = (w*2+0)*512, la1 = (w*2+1)*512;
    const int lb0 = 6144 + (w*4+0)*512, lb1 = 6144 + (w*4+1)*512;
    const int lb2 = 6144 + (w*4+2)*512, lb3 = 6144 + (w*4+3)*512;

#define STGALL(ko, bb) do { \
        u16* Lb = lds + (bb)*18432 + l*8; \
        gload16(gA0k      + (ko), Lb + la0); \
        gload16(gA0k + 32 + (ko), Lb + la1); \
        gload16(gB00      + (ko), Lb + lb0); \
        gload16(gB00 + 32 + (ko), Lb + lb1); \
        gload16(gB10      + (ko), Lb + lb2); \
        gload16(gB10 + 32 + (ko), Lb + lb3); \
    } while(0)

    floatx4 acc[6][2] = {};
    STGALL(0, 0);                                      // prologue: tile 0
    #pragma unroll 1
    for (int kt=0; kt<8; ++kt){
        const int cur = kt&1, nxt = cur^1;
        const int ko = (kt+1)*64;
        if (kt < 7){
            STGALL(ko, nxt);
            asm volatile("s_waitcnt vmcnt(6)" ::: "memory");   // tile kt landed
        } else {
            asm volatile("s_waitcnt vmcnt(0)" ::: "memory");
        }
        __builtin_amdgcn_s_barrier();
        asm volatile("" ::: "memory");
        const u16* bufc = lds + cur*18432;
        short8 bf00 = *(const short8*)&bufc[lb0 + l*8];
        short8 bf01 = *(const short8*)&bufc[lb1 + l*8];
        short8 bf10 = *(const short8*)&bufc[lb2 + l*8];
        short8 bf11 = *(const short8*)&bufc[lb3 + l*8];
        __builtin_amdgcn_s_setprio(1);
        #pragma unroll
        for (int mi=0;mi<6;mi++){
            short8 a0 = *(const short8*)&bufc[(mi*2+0)*512 + l*8];
            short8 a1 = *(const short8*)&bufc[(mi*2+1)*512 + l*8];
            acc[mi][0] = __builtin_amdgcn_mfma_f32_16x16x32_bf16(a0, bf00, acc[mi][0], 0,0,0);
            acc[mi][0] = __builtin_amdgcn_mfma_f32_16x16x32_bf16(a1, bf01, acc[mi][0], 0,0,0);
            acc[mi][1] = __builtin_amdgcn_mfma_f32_16x16x32_bf16(a0, bf10, acc[mi][1], 0,0,0);
            acc[mi][1] = __builtin_amdgcn_mfma_f32_16x16x32_bf16(a1, bf11, acc[mi][1], 0,0,0);
        }
        __builtin_amdgcn_s_setprio(0);
        asm volatile("" ::: "memory");
        __builtin_amdgcn_s_barrier();                  // buf[cur] reads done
        asm volatile("" ::: "memory");
    }
#undef STGALL
    __syncthreads();          // drain all lgkm; bufs dead -> safe to overwrite
    // ---- phase 2: write QKV chunk-fragment images into LDS (per-wave)
    float* sw = (float*)(lds + 18432 + w*1152);        // 16x36 f32 scratch
    if (w < 4){
        // Q (w 0,1) / K (w 2,3); h = d-half this wave owns
        const int h = w&1;
        u16* cbase = lds + (w>>1)*6144;
        #pragma unroll
        for (int mi=0;mi<6;mi++){
            #pragma unroll
            for (int ni=0;ni<2;ni++)
                #pragma unroll
                for (int r=0;r<4;r++)
                    sw[(lq*4+r)*36 + ni*16 + lr] = acc[mi][ni][r];  // [pix16][d32]
            const float* cp = &sw[lr*36 + lq*8];       // per-wave: DS in-order
            float4 v0 = *(const float4*)cp;
            float4 v1 = *(const float4*)(cp+4);
            uint4 sv;
            sv.x = pack2(v0.x,v0.y); sv.y = pack2(v0.z,v0.w);
            sv.z = pack2(v1.x,v1.y); sv.w = pack2(v1.z,v1.w);
            *(uint4*)(cbase + (mi*2 + h)*512 + l*8) = sv;
        }
    } else {
        // V (w 4,5): chunks (dt = h*2+ni, jt)
        const int h = w&1;
        u16* cbase = lds + 12288;
        #pragma unroll
        for (int ni=0;ni<2;ni++){
            #pragma unroll
            for (int jt=0;jt<3;jt++){
                #pragma unroll
                for (int m2=0;m2<2;m2++)
                    #pragma unroll
                    for (int r=0;r<4;r++)
                        sw[lr*36 + m2*16 + lq*4 + r] = acc[jt*2+m2][ni][r];  // [d16][j32]
                const float* cp = &sw[lr*36 + lq*8];
                float4 v0 = *(const float4*)cp;
                float4 v1 = *(const float4*)(cp+4);
                uint4 sv;
                sv.x = pack2(v0.x,v0.y); sv.y = pack2(v0.z,v0.w);
                sv.z = pack2(v1.x,v1.y); sv.w = pack2(v1.z,v1.w);
                *(uint4*)(cbase + ((h*2+ni)*3 + jt)*512 + l*8) = sv;
            }
        }
    }
    __syncthreads();          // chunks visible to all waves
    // ---- phase 3: attention, wave w = q-tile qt (R5-verified code, LDS src)
    {
        const int qt = w;
        const u16* qc = lds;
        const u16* kc = lds + 6144;
        const u16* vc = lds + 12288;
        short8 qf0 = *(const short8*)&qc[(qt*2+0)*512 + l*8];
        short8 qf1 = *(const short8*)&qc[(qt*2+1)*512 + l*8];
        floatx4 sa[6];
        #pragma unroll
        for (int jt=0;jt<6;jt++){
            short8 k0 = *(const short8*)&kc[(jt*2+0)*512 + l*8];
            short8 k1 = *(const short8*)&kc[(jt*2+1)*512 + l*8];
            floatx4 a = {};
            a = __builtin_amdgcn_mfma_f32_16x16x32_bf16(k0, qf0, a, 0,0,0);
            a = __builtin_amdgcn_mfma_f32_16x16x32_bf16(k1, qf1, a, 0,0,0);
            sa[jt] = a;
        }
        float m = -1e30f;
        #pragma unroll
        for (int jt=0;jt<6;jt++)
            #pragma unroll
            for (int r=0;r<4;r++){ sa[jt][r] *= SCALE; m = fmaxf(m, sa[jt][r]); }
        m = fmaxf(m, __shfl_xor(m, 16));
        m = fmaxf(m, __shfl_xor(m, 32));
        float sum = 0.f;
        u32 pk0[6], pk1[6];
        #pragma unroll
        for (int jt=0;jt<6;jt++){
            float e0 = __expf(sa[jt][0]-m), e1 = __expf(sa[jt][1]-m);
            float e2 = __expf(sa[jt][2]-m), e3 = __expf(sa[jt][3]-m);
            sum += e0+e1+e2+e3;
            pk0[jt] = pack2(e0,e1);
            pk1[jt] = pack2(e2,e3);
        }
        sum += __shfl_xor(sum, 16);
        sum += __shfl_xor(sum, 32);
        const float rinv = 1.f/sum;
        const int srcA = lr + ((lq&1)<<5);
        const int srcB = srcA + 16;
        const int hi   = lq>>1;
        short8 pf[3];
        #pragma unroll
        for (int kb=0;kb<3;kb++){
            u32 x0=__shfl(pk0[kb*2],srcA), y0=__shfl(pk0[kb*2+1],srcA);
            u32 x1=__shfl(pk1[kb*2],srcA), y1=__shfl(pk1[kb*2+1],srcA);
            u32 x2=__shfl(pk0[kb*2],srcB), y2=__shfl(pk0[kb*2+1],srcB);
            u32 x3=__shfl(pk1[kb*2],srcB), y3=__shfl(pk1[kb*2+1],srcB);
            pf[kb] = mk8(hi?y0:x0, hi?y1:x1, hi?y2:x2, hi?y3:x3);
        }
        floatx4 o[4] = {};
        #pragma unroll
        for (int kb=0;kb<3;kb++){
            #pragma unroll
            for (int dt=0;dt<4;dt++){
                short8 vf = *(const short8*)&vc[(dt*3+kb)*512 + l*8];
                o[dt] = __builtin_amdgcn_mfma_f32_16x16x32_bf16(vf, pf[kb], o[dt], 0,0,0);
            }
        }
        const size_t pixrow = (size_t)bat*NPIX + row*WW + qt*16;
        u16* ob = attno + (pixrow + lr)*512 + head*64 + lq*4;
        #pragma unroll
        for (int dt=0;dt<4;dt++){
            uint2 st;
            st.x = pack2(o[dt][0]*rinv, o[dt][1]*rinv);
            st.y = pack2(o[dt][2]*rinv, o[dt][3]*rinv);
            *(uint2*)(ob + dt*16) = st;
        }
    }
}

// ---------------------------------------------------------------------------
// MFMA GEMM 2: out[b][n][pix] = attn_ws[m][k] * wob[n][k] + bias[n]
// 128x128 tile, BK=64, 4 waves (2M x 2N), 64 KB LDS -> 2 blocks/CU.
// Grid 1152 = 8 XCDs x 144.
// ---------------------------------------------------------------------------
__global__ __launch_bounds__(256, 2)
void gemm_out(const u16* __restrict__ A, const u16* __restrict__ B,
              const void* __restrict__ bias, const int* __restrict__ flag,
              void* __restrict__ outv){
    __shared__ __align__(16) union ShMem {
        u16 tiles[32768];            // 2 bufs x (A 8192 + B 8192) u16 = 64 KiB
        float ct[4][16][68];
    } sh;
    u16* lds = sh.tiles;
    const int id = blockIdx.x;
    const int xcd = id & 7, slot = id >> 3;        // 1152 = 8 x 144
    const int by = xcd*36 + (slot>>2);
    const int bx = slot & 3;
    const int t = threadIdx.x;
    const int w = t>>6, l = t&63, lr = l&15, lq = l>>4;
    const int wm = w>>1, wn = w&1;                 // wave = 64(M) x 64(N)
    const int m0 = by*128, n0 = bx*128;
    const u16* gA = A + (size_t)(m0 + w*16 + lr)*DIM + lq*8;
    const u16* gB = B + (size_t)(n0 + w*16 + lr)*DIM + lq*8;

#define STG_A(h, ko, bb) do { \
        const u16* _g = gA + (size_t)(h)*32768 + (ko); \
        u16* _l = lds + (bb)*16384 + ((h)*4 + w)*1024; \
        gload16(_g,      _l); \
        gload16(_g + 32, _l + 512); \
    } while(0)
#define STG_B(h, ko, bb) do { \
        const u16* _g = gB + (size_t)(h)*32768 + (ko); \
        u16* _l = lds + (bb)*16384 + 8192 + ((h)*4 + w)*1024; \
        gload16(_g,      _l); \
        gload16(_g + 32, _l + 512); \
    } while(0)

    floatx4 acc[4][4] = {};
    STG_A(0,0,0); STG_A(1,0,0); STG_B(0,0,0); STG_B(1,0,0);

    #pragma unroll 1
    for (int kt=0; kt<8; ++kt){
        const int cur = kt&1, nxt = cur^1;
        const int ko = (kt+1)*64;
        if (kt < 7){
            STG_A(0, ko, nxt);
            asm volatile("s_waitcnt vmcnt(2)" ::: "memory");
        } else {
            asm volatile("s_waitcnt vmcnt(0)" ::: "memory");
        }
        __builtin_amdgcn_s_barrier();
        asm volatile("" ::: "memory");
        const u16* bA = lds + cur*16384 +        wm*4096 + l*8;
        const u16* bB = lds + cur*16384 + 8192 + wn*4096 + l*8;
        short8 af[4][2], bf[2][2];
        // ---- phase 0: read A + B-lo; stage A1; MFMA n-tiles 0,1
        #pragma unroll
        for (int mi=0;mi<4;mi++){
            af[mi][0] = *(const short8*)(bA + mi*1024);
            af[mi][1] = *(const short8*)(bA + mi*1024 + 512);
        }
        #pragma unroll
        for (int ni=0;ni<2;ni++){
            bf[ni][0] = *(const short8*)(bB + ni*1024);
            bf[ni][1] = *(const short8*)(bB + ni*1024 + 512);
        }
        if (kt < 7) STG_A(1, ko, nxt);
        asm volatile("" ::: "memory");
        __builtin_amdgcn_s_barrier();
        __builtin_amdgcn_sched_barrier(0);
        __builtin_amdgcn_s_setprio(1);
        #pragma unroll
        for (int mi=0;mi<4;mi++)
            #pragma unroll
            for (int ni=0;ni<2;ni++){
                acc[mi][ni] = __builtin_amdgcn_mfma_f32_16x16x32_bf16(af[mi][0], bf[ni][0], acc[mi][ni], 0,0,0);
                acc[mi][ni] = __builtin_amdgcn_mfma_f32_16x16x32_bf16(af[mi][1], bf[ni][1], acc[mi][ni], 0,0,0);
            }
        __builtin_amdgcn_s_setprio(0);
        __builtin_amdgcn_sched_barrier(0);
        __builtin_amdgcn_s_barrier();
        // ---- phase 1: read B-hi; stage B0+B1; MFMA n-tiles 2,3
        #pragma unroll
        for (int ni=0;ni<2;ni++){
            bf[ni][0] = *(const short8*)(bB + (2+ni)*1024);
            bf[ni][1] = *(const short8*)(bB + (2+ni)*1024 + 512);
        }
        if (kt < 7){ STG_B(0, ko, nxt); STG_B(1, ko, nxt); }
        asm volatile("" ::: "memory");
        __builtin_amdgcn_s_barrier();
        __builtin_amdgcn_sched_barrier(0);
        __builtin_amdgcn_s_setprio(1);
        #pragma unroll
        for (int mi=0;mi<4;mi++)
            #pragma unroll
            for (int ni=0;ni<2;ni++){
                acc[mi][2+ni] = __builtin_amdgcn_mfma_f32_16x16x32_bf16(af[mi][0], bf[ni][0], acc[mi][2+ni], 0,0,0);
                acc[mi][2+ni] = __builtin_amdgcn_mfma_f32_16x16x32_bf16(af[mi][1], bf[ni][1], acc[mi][2+ni], 0,0,0);
            }
        __builtin_amdgcn_s_setprio(0);
        __builtin_amdgcn_sched_barrier(0);
        asm volatile("" ::: "memory");
        __builtin_amdgcn_s_barrier();
        asm volatile("" ::: "memory");
    }
#undef STG_A
#undef STG_B
    const int isb = *flag;
    const int bat  = m0 / NPIX;
    const int pix0 = (m0 - bat*NPIX) + wm*64;
    float (*ct)[68] = sh.ct[w];
    const u16*   b16 = (const u16*)bias;
    const float* b32 = (const float*)bias;
    const int nl = l>>2, seg = l&3;
    for (int ni=0; ni<4; ni++){
        #pragma unroll
        for (int mi=0;mi<4;mi++)
            #pragma unroll
            for (int r=0;r<4;r++)
                ct[lr][mi*16 + lq*4 + r] = acc[mi][ni][r];   // [n16][pix64]
        int ng = n0 + wn*64 + ni*16 + nl;
        float bv = isb ? b2f(b16[ng]) : b32[ng];
        const float* cp = &ct[nl][seg*16];
        float4 v0 = *(const float4*)(cp);
        float4 v1 = *(const float4*)(cp+4);
        float4 v2 = *(const float4*)(cp+8);
        float4 v3 = *(const float4*)(cp+12);
        v0.x+=bv; v0.y+=bv; v0.z+=bv; v0.w+=bv;
        v1.x+=bv; v1.y+=bv; v1.z+=bv; v1.w+=bv;
        v2.x+=bv; v2.y+=bv; v2.z+=bv; v2.w+=bv;
        v3.x+=bv; v3.y+=bv; v3.z+=bv; v3.w+=bv;
        size_t off = ((size_t)(bat*DIM + ng))*NPIX + pix0 + seg*16;
        if (isb){
            uint4 s0, s1;
            s0.x=pack2(v0.x,v0.y); s0.y=pack2(v0.z,v0.w);
            s0.z=pack2(v1.x,v1.y); s0.w=pack2(v1.z,v1.w);
            s1.x=pack2(v2.x,v2.y); s1.y=pack2(v2.z,v2.w);
            s1.z=pack2(v3.x,v3.y); s1.w=pack2(v3.z,v3.w);
            *(uint4*)((u16*)outv + off)     = s0;
            *(uint4*)((u16*)outv + off + 8) = s1;
        } else {
            float* of = (float*)outv + off;
            *(float4*)(of)    = v0;
            *(float4*)(of+4)  = v1;
            *(float4*)(of+8)  = v2;
            *(float4*)(of+12) = v3;
        }
    }
}

extern "C" void kernel_launch(void* const* d_in, const int* in_sizes, int n_in,
                              void* d_out, int out_size, void* d_ws, size_t ws_size,
                              hipStream_t stream){
    const void* x    = d_in[0];
    const void* wqkv = d_in[1];
    const void* wout = d_in[2];
    const void* bout = d_in[3];
    char* wsb = (char*)d_ws;
    int* flag    = (int*)wsb;                                  // 256 B
    u16* xb      = (u16*)(wsb + 256);                          // [36864][512] bf16
    u16* wqb     = xb + (size_t)M_TOT*DIM;                     // [1536][512]
    u16* wob     = wqb + (size_t)N_QKV*DIM;                    // [512][512]
    u16* attn_ws = wob + (size_t)DIM*DIM;                      // [36864][512] bf16
    detect_dtype<<<1, 256, 0, stream>>>((const u16*)wqkv, flag);
    convert_w<<<4096, 256, 0, stream>>>(wqkv, wout, flag, wqb, wob);
    convert_x<<<dim3(144, 8, 4), 256, 0, stream>>>(x, flag, xb);
    qkv_attn<<<3072, 384, 0, stream>>>(xb, wqb, attn_ws);
    gemm_out<<<1152, 256, 0, stream>>>(attn_ws, wob, bout, flag, d_out);
}